// Round 11
// baseline (234.474 us; speedup 1.0000x reference)
//
#include <hip/hip_runtime.h>

typedef float vf2 __attribute__((ext_vector_type(2)));
typedef float vf4 __attribute__((ext_vector_type(4)));

// DPP move: compile-time control, bound_ctrl=1 (out-of-range lanes read 0)
template<int CTRL>
__device__ __forceinline__ float dppf(float v) {
    return __int_as_float(__builtin_amdgcn_update_dpp(
        0, __float_as_int(v), CTRL, 0xF, 0xF, true));
}

// Sum across each 8-lane half-row; result valid on ALL 8 lanes.
__device__ __forceinline__ float bfly8(float v) {
    v += dppf<0xB1>(v);    // quad_perm [1,0,3,2]  (xor 1)
    v += dppf<0x4E>(v);    // quad_perm [2,3,0,1]  (xor 2)
    v += dppf<0x141>(v);   // row_half_mirror      (joins the two quads)
    return v;
}

#define BATCH_F 264                  // 256 + 8 pad: write banks hit exactly 2x (wave min)
#define ROUND_F (4 * BATCH_F + 4)    // 4 staged batches + 4 scales = 1060 dwords (4240 B)

// LDS 16960 B/block -> 9 blocks/CU by LDS; VGPR<=73 -> ~7-8 waves/SIMD.
__global__ __launch_bounds__(256, 7) void apply_area_kernel(
    const float* __restrict__ img_g,
    const float* __restrict__ mn_g,
    const float* __restrict__ mo_g,
    float* __restrict__ out,
    int B)
{
    __shared__ float smem[4 * ROUND_F];

    const int lane = threadIdx.x & 63;
    const int w    = threadIdx.x >> 6;
    const int q    = lane >> 3;      // batch within wave (8 per wave)
    const int l    = lane & 7;       // column-pair: owns cols 2l, 2l+1
    const int b    = blockIdx.x * 32 + w * 8 + q;
    if (b >= B) return;

    const vf2* im2 = reinterpret_cast<const vf2*>(img_g) + (size_t)b * 128 + l;
    const vf2* mn2 = reinterpret_cast<const vf2*>(mn_g)  + (size_t)b * 64  + l;
    const vf2* mo2 = reinterpret_cast<const vf2*>(mo_g)  + (size_t)b * 64  + l;

    float imx[16], imy[16], mcx[16], mcy[16];
#pragma unroll
    for (int r = 0; r < 16; ++r) { vf2 v = im2[r * 8]; imx[r] = v.x; imy[r] = v.y; }
#pragma unroll
    for (int i = 0; i < 8; ++i) {   // mc row 2i = mn[i], row 2i+1 = mo[i]
        vf2 a = mn2[i * 8]; mcx[2*i]   = a.x; mcy[2*i]   = a.y;
        vf2 o = mo2[i * 8]; mcx[2*i+1] = o.x; mcy[2*i+1] = o.y;
    }
    asm volatile("" ::: "memory");

    // ---- consistency (rows in-register) ----
    float c_acc = 0.f;
#pragma unroll
    for (int i = 0; i < 8; ++i) {
        float mx_m = (i > 0) ? mcx[2*i-1] : 0.f, my_m = (i > 0) ? mcy[2*i-1] : 0.f;
        float mx_p = (i < 7) ? mcx[2*i+3] : 0.f, my_p = (i < 7) ? mcy[2*i+3] : 0.f;
        float gx = 0.5f * (mx_p - mx_m), gy = 0.5f * (my_p - my_m);
        c_acc += fmaxf(mcx[2*i] - 5.f * (gx*gx + mcx[2*i+1]), 0.f);
        c_acc += fmaxf(mcy[2*i] - 5.f * (gy*gy + mcy[2*i+1]), 0.f);
    }

    // ---- edge / rounding / avg_cov / column-pair sums ----
    float e_acc = 0.f, r_acc = 0.f, a_acc = 0.f, smi = 0.f, S1 = 0.f, S2 = 0.f;
    const int c0 = 2 * l, c1 = 2 * l + 1;
#pragma unroll
    for (int r = 0; r < 16; ++r) {
        int abr = (r > 7) ? r - 7 : 7 - r;
        bool drow = (r < 15);
#define COMP(imA, mcA, cc) { \
        float gi = (r == 0)  ? imA[1] - imA[0] \
                 : (r == 15) ? imA[15] - imA[14] \
                 : 0.5f * (imA[r + 1] - imA[r - 1]); \
        float gm = (r == 0)  ? mcA[1] - mcA[0] \
                 : (r == 15) ? mcA[15] - mcA[14] \
                 : 0.5f * (mcA[r + 1] - mcA[r - 1]); \
        float d = gi - gm; e_acc += 0.5f * d * d * gi; \
        float tw = 2.f * mcA[r] - 1.f; r_acc += tw * tw; \
        float dia = (drow && (cc) >= abr && (cc) <= 14 - abr) ? 1.f : 0.f; \
        float dd = mcA[r] - dia; a_acc += 0.5f * dd * dd; \
        S1 += mcA[r]; S2 += mcA[r] * mcA[r]; smi += mcA[r] * imA[r]; }
        COMP(imx, mcx, c0)
        COMP(imy, mcy, c1)
#undef COMP
    }

    // ---- 4 translations: B=Σt·im, D=Σt³·im, E=Σ(t²·im)² ----
    const float mz7 = (l == 7) ? 0.f : 1.f;
    const float mz0 = (l == 0) ? 0.f : 1.f;
    float B0=0,D0=0,E0=0, B1=0,D1=0,E1=0, B2=0,D2=0,E2=0, B3=0,D3=0,E3=0;
#pragma unroll
    for (int r = 0; r < 16; ++r) {
        float t0x = (r < 14) ? mcx[r+2] : 0.f, t0y = (r < 14) ? mcy[r+2] : 0.f;
        float t1x = (r >= 2) ? mcx[r-2] : 0.f, t1y = (r >= 2) ? mcy[r-2] : 0.f;
        float t2x = dppf<0x101>(mcx[r]) * mz7, t2y = dppf<0x101>(mcy[r]) * mz7;
        float t3x = dppf<0x111>(mcx[r]) * mz0, t3y = dppf<0x111>(mcy[r]) * mz0;
#define ACC2(tx, ty, Bx, Dx, Ex) { \
        float mix_ = (tx) * imx[r], miy_ = (ty) * imy[r]; \
        Bx += mix_ + miy_; \
        Dx += (tx)*(tx)*mix_ + (ty)*(ty)*miy_; \
        float ax_ = (tx)*mix_, ay_ = (ty)*miy_; \
        Ex += ax_*ax_ + ay_*ay_; }
        ACC2(t0x, t0y, B0, D0, E0)
        ACC2(t1x, t1y, B1, D1, E1)
        ACC2(t2x, t2y, B2, D2, E2)
        ACC2(t3x, t3y, B3, D3, E3)
#undef ACC2
    }
    float A0 = S1 - (mcx[0] + mcy[0] + mcx[1] + mcy[1]);
    float C0 = S2 - (mcx[0]*mcx[0] + mcy[0]*mcy[0] + mcx[1]*mcx[1] + mcy[1]*mcy[1]);
    float A1 = S1 - (mcx[14] + mcy[14] + mcx[15] + mcy[15]);
    float C1 = S2 - (mcx[14]*mcx[14] + mcy[14]*mcy[14] + mcx[15]*mcx[15] + mcy[15]*mcy[15]);
    float A2 = dppf<0x101>(S1) * mz7, C2 = dppf<0x101>(S2) * mz7;
    float A3 = dppf<0x111>(S1) * mz0, C3 = dppf<0x111>(S2) * mz0;

    // ---- 26 half-row reductions, all DPP on the VALU pipe ----
    c_acc = bfly8(c_acc); r_acc = bfly8(r_acc);
    e_acc = bfly8(e_acc); a_acc = bfly8(a_acc);
    float smc = bfly8(S1); smi = bfly8(smi);
    A0 = bfly8(A0); A1 = bfly8(A1); A2 = bfly8(A2); A3 = bfly8(A3);
    B0 = bfly8(B0); B1 = bfly8(B1); B2 = bfly8(B2); B3 = bfly8(B3);
    C0 = bfly8(C0); C1 = bfly8(C1); C2 = bfly8(C2); C3 = bfly8(C3);
    D0 = bfly8(D0); D1 = bfly8(D1); D2 = bfly8(D2); D3 = bfly8(D3);
    E0 = bfly8(E0); E1 = bfly8(E1); E2 = bfly8(E2); E3 = bfly8(E3);

    const float scale = smi / smc;

    // ---- dense store path: two 4-batch staging rounds (wave-private, no
    //      barriers; DS pipe is in-order per wave so WAR across rounds is safe).
    //      out_image is derived on READBACK (mc_quad * scale[c]) -> one staging
    //      pass serves both output streams. ----
    float* wbuf = smem + w * ROUND_F;
    const int batchBase = blockIdx.x * 32 + w * 8;
    float* oib = out + (size_t)B * 256;

#pragma unroll
    for (int half = 0; half < 2; ++half) {
        if ((q >> 2) == half) {
            float* wb = wbuf + (q & 3) * BATCH_F;
#pragma unroll
            for (int r = 0; r < 16; ++r) {
                vf2 mv; mv.x = mcx[r]; mv.y = mcy[r];
                *reinterpret_cast<vf2*>(wb + r * 16 + 2 * l) = mv;
            }
            if (l == 0) wbuf[4 * BATCH_F + (q & 3)] = scale;
        }
        asm volatile("s_waitcnt lgkmcnt(0)" ::: "memory");
        vf4 scv = *reinterpret_cast<const vf4*>(wbuf + 4 * BATCH_F);
#pragma unroll
        for (int c = 0; c < 4; ++c) {
            const int bb = batchBase + half * 4 + c;
            vf4 v = *reinterpret_cast<const vf4*>(wbuf + c * BATCH_F + lane * 4);
            float sc = (c == 0) ? scv.x : (c == 1) ? scv.y : (c == 2) ? scv.z : scv.w;
            __builtin_nontemporal_store(v,
                reinterpret_cast<vf4*>(out + (size_t)bb * 256) + lane);
            __builtin_nontemporal_store(v * sc,
                reinterpret_cast<vf4*>(oib + (size_t)bb * 256) + lane);
        }
        asm volatile("" ::: "memory");
    }

    if (l == 0) {
        float m0 = B0 / A0, m1 = B1 / A1, m2 = B2 / A2, m3 = B3 / A3;
        float v0 = (E0 - 2.f * m0 * D0 + m0 * m0 * C0) / A0;
        float v1 = (E1 - 2.f * m1 * D1 + m1 * m1 * C1) / A1;
        float v2 = (E2 - 2.f * m2 * D2 + m2 * m2 * C2) / A2;
        float v3 = (E3 - 2.f * m3 * D3 + m3 * m3 * C3) / A3;
        float fm = 0.25f * (m0 + m1 + m2 + m3);
        float dm0 = m0 - fm, dm1 = m1 - fm, dm2 = m2 - fm, dm3 = m3 - fm;
        float vm = 0.25f * (dm0*dm0 + dm1*dm1 + dm2*dm2 + dm3*dm3);
        float fv = 0.25f * (v0 + v1 + v2 + v3);
        float dv0 = v0 - fv, dv1 = v1 - fv, dv2 = v2 - fv, dv3 = v3 - fv;
        float vv = 0.25f * (dv0*dv0 + dv1*dv1 + dv2*dv2 + dv3*dv3);

        float* s = out + (size_t)B * 512;
        __builtin_nontemporal_store(c_acc * (1.f / 128.f), s + b);
        __builtin_nontemporal_store(-r_acc * (1.f / 256.f), s + (size_t)B + b);
        __builtin_nontemporal_store(0.5f * (vm + vv), s + 2*(size_t)B + b);
        __builtin_nontemporal_store(e_acc * (1.f / 256.f), s + 3*(size_t)B + b);
        __builtin_nontemporal_store(a_acc * (1.f / 256.f), s + 4*(size_t)B + b);
    }
}

extern "C" void kernel_launch(void* const* d_in, const int* in_sizes, int n_in,
                              void* d_out, int out_size, void* d_ws, size_t ws_size,
                              hipStream_t stream) {
    const float* img = (const float*)d_in[0];
    const float* mn  = (const float*)d_in[1];
    const float* mo  = (const float*)d_in[2];
    float* out = (float*)d_out;
    const int B = in_sizes[0] / 256;
    const int blocks = (B + 31) / 32;   // 32 batches per 256-thread block
    apply_area_kernel<<<blocks, 256, 0, stream>>>(img, mn, mo, out, B);
}

// Round 12
// 89.224 us; speedup vs baseline: 2.6279x; 2.6279x over previous
//
#include <hip/hip_runtime.h>

typedef float vf2 __attribute__((ext_vector_type(2)));
typedef float vf4 __attribute__((ext_vector_type(4)));

// DPP move: compile-time control, bound_ctrl=1 (out-of-range lanes read 0)
template<int CTRL>
__device__ __forceinline__ float dppf(float v) {
    return __int_as_float(__builtin_amdgcn_update_dpp(
        0, __float_as_int(v), CTRL, 0xF, 0xF, true));
}

// Sum across each 8-lane half-row; result valid on ALL 8 lanes.
__device__ __forceinline__ float bfly8(float v) {
    v += dppf<0xB1>(v);    // quad_perm [1,0,3,2]  (xor 1)
    v += dppf<0x4E>(v);    // quad_perm [2,3,0,1]  (xor 2)
    v += dppf<0x141>(v);   // row_half_mirror      (joins the two quads)
    return v;
}

#define BATCH_F 264                  // 256 + 8 pad: write banks hit exactly 2x (wave min)
#define ROUND_F (4 * BATCH_F + 4)    // 4 staged batches + 4 scales = 1060 dwords (4240 B)

// LDS 16960 B/block -> 9 blocks/CU by LDS. launch_bounds(256,4): VGPR cap ~128
// (R11's (256,7) cap forced VGPR=36 + ~625 MB scratch-spill traffic — never again).
__global__ __launch_bounds__(256, 4) void apply_area_kernel(
    const float* __restrict__ img_g,
    const float* __restrict__ mn_g,
    const float* __restrict__ mo_g,
    float* __restrict__ out,
    int B)
{
    __shared__ float smem[4 * ROUND_F];

    const int lane = threadIdx.x & 63;
    const int w    = threadIdx.x >> 6;
    const int q    = lane >> 3;      // batch within wave (8 per wave)
    const int l    = lane & 7;       // column-pair: owns cols 2l, 2l+1
    const int b    = blockIdx.x * 32 + w * 8 + q;
    if (b >= B) return;

    const vf2* im2 = reinterpret_cast<const vf2*>(img_g) + (size_t)b * 128 + l;
    const vf2* mn2 = reinterpret_cast<const vf2*>(mn_g)  + (size_t)b * 64  + l;
    const vf2* mo2 = reinterpret_cast<const vf2*>(mo_g)  + (size_t)b * 64  + l;

    float imx[16], imy[16], mcx[16], mcy[16];
#pragma unroll
    for (int r = 0; r < 16; ++r) { vf2 v = im2[r * 8]; imx[r] = v.x; imy[r] = v.y; }
#pragma unroll
    for (int i = 0; i < 8; ++i) {   // mc row 2i = mn[i], row 2i+1 = mo[i]
        vf2 a = mn2[i * 8]; mcx[2*i]   = a.x; mcy[2*i]   = a.y;
        vf2 o = mo2[i * 8]; mcx[2*i+1] = o.x; mcy[2*i+1] = o.y;
    }
    asm volatile("" ::: "memory");

    // ---- consistency (rows in-register) ----
    float c_acc = 0.f;
#pragma unroll
    for (int i = 0; i < 8; ++i) {
        float mx_m = (i > 0) ? mcx[2*i-1] : 0.f, my_m = (i > 0) ? mcy[2*i-1] : 0.f;
        float mx_p = (i < 7) ? mcx[2*i+3] : 0.f, my_p = (i < 7) ? mcy[2*i+3] : 0.f;
        float gx = 0.5f * (mx_p - mx_m), gy = 0.5f * (my_p - my_m);
        c_acc += fmaxf(mcx[2*i] - 5.f * (gx*gx + mcx[2*i+1]), 0.f);
        c_acc += fmaxf(mcy[2*i] - 5.f * (gy*gy + mcy[2*i+1]), 0.f);
    }

    // ---- edge / rounding / avg_cov / column-pair sums ----
    float e_acc = 0.f, r_acc = 0.f, a_acc = 0.f, smi = 0.f, S1 = 0.f, S2 = 0.f;
    const int c0 = 2 * l, c1 = 2 * l + 1;
#pragma unroll
    for (int r = 0; r < 16; ++r) {
        int abr = (r > 7) ? r - 7 : 7 - r;
        bool drow = (r < 15);
#define COMP(imA, mcA, cc) { \
        float gi = (r == 0)  ? imA[1] - imA[0] \
                 : (r == 15) ? imA[15] - imA[14] \
                 : 0.5f * (imA[r + 1] - imA[r - 1]); \
        float gm = (r == 0)  ? mcA[1] - mcA[0] \
                 : (r == 15) ? mcA[15] - mcA[14] \
                 : 0.5f * (mcA[r + 1] - mcA[r - 1]); \
        float d = gi - gm; e_acc += 0.5f * d * d * gi; \
        float tw = 2.f * mcA[r] - 1.f; r_acc += tw * tw; \
        float dia = (drow && (cc) >= abr && (cc) <= 14 - abr) ? 1.f : 0.f; \
        float dd = mcA[r] - dia; a_acc += 0.5f * dd * dd; \
        S1 += mcA[r]; S2 += mcA[r] * mcA[r]; smi += mcA[r] * imA[r]; }
        COMP(imx, mcx, c0)
        COMP(imy, mcy, c1)
#undef COMP
    }

    // ---- 4 translations: B=Σt·im, D=Σt³·im, E=Σ(t²·im)² ----
    const float mz7 = (l == 7) ? 0.f : 1.f;
    const float mz0 = (l == 0) ? 0.f : 1.f;
    float B0=0,D0=0,E0=0, B1=0,D1=0,E1=0, B2=0,D2=0,E2=0, B3=0,D3=0,E3=0;
#pragma unroll
    for (int r = 0; r < 16; ++r) {
        float t0x = (r < 14) ? mcx[r+2] : 0.f, t0y = (r < 14) ? mcy[r+2] : 0.f;
        float t1x = (r >= 2) ? mcx[r-2] : 0.f, t1y = (r >= 2) ? mcy[r-2] : 0.f;
        float t2x = dppf<0x101>(mcx[r]) * mz7, t2y = dppf<0x101>(mcy[r]) * mz7;
        float t3x = dppf<0x111>(mcx[r]) * mz0, t3y = dppf<0x111>(mcy[r]) * mz0;
#define ACC2(tx, ty, Bx, Dx, Ex) { \
        float mix_ = (tx) * imx[r], miy_ = (ty) * imy[r]; \
        Bx += mix_ + miy_; \
        Dx += (tx)*(tx)*mix_ + (ty)*(ty)*miy_; \
        float ax_ = (tx)*mix_, ay_ = (ty)*miy_; \
        Ex += ax_*ax_ + ay_*ay_; }
        ACC2(t0x, t0y, B0, D0, E0)
        ACC2(t1x, t1y, B1, D1, E1)
        ACC2(t2x, t2y, B2, D2, E2)
        ACC2(t3x, t3y, B3, D3, E3)
#undef ACC2
    }
    float A0 = S1 - (mcx[0] + mcy[0] + mcx[1] + mcy[1]);
    float C0 = S2 - (mcx[0]*mcx[0] + mcy[0]*mcy[0] + mcx[1]*mcx[1] + mcy[1]*mcy[1]);
    float A1 = S1 - (mcx[14] + mcy[14] + mcx[15] + mcy[15]);
    float C1 = S2 - (mcx[14]*mcx[14] + mcy[14]*mcy[14] + mcx[15]*mcx[15] + mcy[15]*mcy[15]);
    float A2 = dppf<0x101>(S1) * mz7, C2 = dppf<0x101>(S2) * mz7;
    float A3 = dppf<0x111>(S1) * mz0, C3 = dppf<0x111>(S2) * mz0;

    // ---- 26 half-row reductions, all DPP on the VALU pipe ----
    c_acc = bfly8(c_acc); r_acc = bfly8(r_acc);
    e_acc = bfly8(e_acc); a_acc = bfly8(a_acc);
    float smc = bfly8(S1); smi = bfly8(smi);
    A0 = bfly8(A0); A1 = bfly8(A1); A2 = bfly8(A2); A3 = bfly8(A3);
    B0 = bfly8(B0); B1 = bfly8(B1); B2 = bfly8(B2); B3 = bfly8(B3);
    C0 = bfly8(C0); C1 = bfly8(C1); C2 = bfly8(C2); C3 = bfly8(C3);
    D0 = bfly8(D0); D1 = bfly8(D1); D2 = bfly8(D2); D3 = bfly8(D3);
    E0 = bfly8(E0); E1 = bfly8(E1); E2 = bfly8(E2); E3 = bfly8(E3);

    const float scale = smi / smc;

    // ---- dense store path: two 4-batch staging rounds (wave-private, no
    //      barriers; DS pipe is in-order per wave so WAR across rounds is safe).
    //      out_image derived on READBACK (mc_quad * scale[c]). ----
    float* wbuf = smem + w * ROUND_F;
    const int batchBase = blockIdx.x * 32 + w * 8;
    float* oib = out + (size_t)B * 256;

#pragma unroll
    for (int half = 0; half < 2; ++half) {
        if ((q >> 2) == half) {
            float* wb = wbuf + (q & 3) * BATCH_F;
#pragma unroll
            for (int r = 0; r < 16; ++r) {
                vf2 mv; mv.x = mcx[r]; mv.y = mcy[r];
                *reinterpret_cast<vf2*>(wb + r * 16 + 2 * l) = mv;
            }
            if (l == 0) wbuf[4 * BATCH_F + (q & 3)] = scale;
        }
        asm volatile("s_waitcnt lgkmcnt(0)" ::: "memory");
        vf4 scv = *reinterpret_cast<const vf4*>(wbuf + 4 * BATCH_F);
#pragma unroll
        for (int c = 0; c < 4; ++c) {
            const int bb = batchBase + half * 4 + c;
            vf4 v = *reinterpret_cast<const vf4*>(wbuf + c * BATCH_F + lane * 4);
            float sc = (c == 0) ? scv.x : (c == 1) ? scv.y : (c == 2) ? scv.z : scv.w;
            __builtin_nontemporal_store(v,
                reinterpret_cast<vf4*>(out + (size_t)bb * 256) + lane);
            __builtin_nontemporal_store(v * sc,
                reinterpret_cast<vf4*>(oib + (size_t)bb * 256) + lane);
        }
        asm volatile("" ::: "memory");
    }

    if (l == 0) {
        float m0 = B0 / A0, m1 = B1 / A1, m2 = B2 / A2, m3 = B3 / A3;
        float v0 = (E0 - 2.f * m0 * D0 + m0 * m0 * C0) / A0;
        float v1 = (E1 - 2.f * m1 * D1 + m1 * m1 * C1) / A1;
        float v2 = (E2 - 2.f * m2 * D2 + m2 * m2 * C2) / A2;
        float v3 = (E3 - 2.f * m3 * D3 + m3 * m3 * C3) / A3;
        float fm = 0.25f * (m0 + m1 + m2 + m3);
        float dm0 = m0 - fm, dm1 = m1 - fm, dm2 = m2 - fm, dm3 = m3 - fm;
        float vm = 0.25f * (dm0*dm0 + dm1*dm1 + dm2*dm2 + dm3*dm3);
        float fv = 0.25f * (v0 + v1 + v2 + v3);
        float dv0 = v0 - fv, dv1 = v1 - fv, dv2 = v2 - fv, dv3 = v3 - fv;
        float vv = 0.25f * (dv0*dv0 + dv1*dv1 + dv2*dv2 + dv3*dv3);

        float* s = out + (size_t)B * 512;
        __builtin_nontemporal_store(c_acc * (1.f / 128.f), s + b);
        __builtin_nontemporal_store(-r_acc * (1.f / 256.f), s + (size_t)B + b);
        __builtin_nontemporal_store(0.5f * (vm + vv), s + 2*(size_t)B + b);
        __builtin_nontemporal_store(e_acc * (1.f / 256.f), s + 3*(size_t)B + b);
        __builtin_nontemporal_store(a_acc * (1.f / 256.f), s + 4*(size_t)B + b);
    }
}

extern "C" void kernel_launch(void* const* d_in, const int* in_sizes, int n_in,
                              void* d_out, int out_size, void* d_ws, size_t ws_size,
                              hipStream_t stream) {
    const float* img = (const float*)d_in[0];
    const float* mn  = (const float*)d_in[1];
    const float* mo  = (const float*)d_in[2];
    float* out = (float*)d_out;
    const int B = in_sizes[0] / 256;
    const int blocks = (B + 31) / 32;   // 32 batches per 256-thread block
    apply_area_kernel<<<blocks, 256, 0, stream>>>(img, mn, mo, out, B);
}

// Round 14
// 89.186 us; speedup vs baseline: 2.6290x; 1.0004x over previous
//
#include <hip/hip_runtime.h>

typedef float vf2 __attribute__((ext_vector_type(2)));
typedef float vf4 __attribute__((ext_vector_type(4)));

// DPP move: compile-time control, bound_ctrl=1 (out-of-range lanes read 0)
template<int CTRL>
__device__ __forceinline__ float dppf(float v) {
    return __int_as_float(__builtin_amdgcn_update_dpp(
        0, __float_as_int(v), CTRL, 0xF, 0xF, true));
}

// Sum across each 8-lane half-row; result valid on ALL 8 lanes.
__device__ __forceinline__ float bfly8(float v) {
    v += dppf<0xB1>(v);    // quad_perm [1,0,3,2]  (xor 1)
    v += dppf<0x4E>(v);    // quad_perm [2,3,0,1]  (xor 2)
    v += dppf<0x141>(v);   // row_half_mirror      (joins the two quads)
    return v;
}

#define BATCH_F 264                  // 256 + 8 pad
#define ROUND_F (4 * BATCH_F + 4)    // 4 staged batches + 4 scales

// Staging layout: logical dword d (0..255) of a batch lives at physical
// 32*(d>>5) + 4*(((d>>2)&7) ^ (d>>5)) + (d&3)  — XOR of the 4-dword slot
// with the 32-dword row. Involution; makes the lane*4 vf4 readback hit all
// banks (was 8-way conflict = 2^20 SQ_LDS_BANK_CONFLICT in R12).
__global__ __launch_bounds__(256, 4) void apply_area_kernel(
    const float* __restrict__ img_g,
    const float* __restrict__ mn_g,
    const float* __restrict__ mo_g,
    float* __restrict__ out,
    int B)
{
    __shared__ float smem[4 * ROUND_F];

    const int lane = threadIdx.x & 63;
    const int w    = threadIdx.x >> 6;
    const int q    = lane >> 3;      // batch within wave (8 per wave)
    const int l    = lane & 7;       // column-pair: owns cols 2l, 2l+1
    const int b    = blockIdx.x * 32 + w * 8 + q;
    if (b >= B) return;

    const vf2* im2 = reinterpret_cast<const vf2*>(img_g) + (size_t)b * 128 + l;
    const vf2* mn2 = reinterpret_cast<const vf2*>(mn_g)  + (size_t)b * 64  + l;
    const vf2* mo2 = reinterpret_cast<const vf2*>(mo_g)  + (size_t)b * 64  + l;

    float imx[16], imy[16], mcx[16], mcy[16];
#pragma unroll
    for (int r = 0; r < 16; ++r) { vf2 v = im2[r * 8]; imx[r] = v.x; imy[r] = v.y; }
#pragma unroll
    for (int i = 0; i < 8; ++i) {   // mc row 2i = mn[i], row 2i+1 = mo[i]
        vf2 a = mn2[i * 8]; mcx[2*i]   = a.x; mcy[2*i]   = a.y;
        vf2 o = mo2[i * 8]; mcx[2*i+1] = o.x; mcy[2*i+1] = o.y;
    }
    asm volatile("" ::: "memory");

    // ---- consistency (rows in-register) ----
    float c_acc = 0.f;
#pragma unroll
    for (int i = 0; i < 8; ++i) {
        float mx_m = (i > 0) ? mcx[2*i-1] : 0.f, my_m = (i > 0) ? mcy[2*i-1] : 0.f;
        float mx_p = (i < 7) ? mcx[2*i+3] : 0.f, my_p = (i < 7) ? mcy[2*i+3] : 0.f;
        float gx = 0.5f * (mx_p - mx_m), gy = 0.5f * (my_p - my_m);
        c_acc += fmaxf(mcx[2*i] - 5.f * (gx*gx + mcx[2*i+1]), 0.f);
        c_acc += fmaxf(mcy[2*i] - 5.f * (gy*gy + mcy[2*i+1]), 0.f);
    }

    // ---- edge / rounding / avg_cov / column-pair sums ----
    float e_acc = 0.f, r_acc = 0.f, a_acc = 0.f, smi = 0.f, S1 = 0.f, S2 = 0.f;
    const int c0 = 2 * l, c1 = 2 * l + 1;
#pragma unroll
    for (int r = 0; r < 16; ++r) {
        int abr = (r > 7) ? r - 7 : 7 - r;
        bool drow = (r < 15);
#define COMP(imA, mcA, cc) { \
        float gi = (r == 0)  ? imA[1] - imA[0] \
                 : (r == 15) ? imA[15] - imA[14] \
                 : 0.5f * (imA[r + 1] - imA[r - 1]); \
        float gm = (r == 0)  ? mcA[1] - mcA[0] \
                 : (r == 15) ? mcA[15] - mcA[14] \
                 : 0.5f * (mcA[r + 1] - mcA[r - 1]); \
        float d = gi - gm; e_acc += 0.5f * d * d * gi; \
        float tw = 2.f * mcA[r] - 1.f; r_acc += tw * tw; \
        float dia = (drow && (cc) >= abr && (cc) <= 14 - abr) ? 1.f : 0.f; \
        float dd = mcA[r] - dia; a_acc += 0.5f * dd * dd; \
        S1 += mcA[r]; S2 += mcA[r] * mcA[r]; smi += mcA[r] * imA[r]; }
        COMP(imx, mcx, c0)
        COMP(imy, mcy, c1)
#undef COMP
    }

    // ---- 4 translations: B=Σt·im, D=Σt³·im, E=Σ(t²·im)² ----
    const float mz7 = (l == 7) ? 0.f : 1.f;
    const float mz0 = (l == 0) ? 0.f : 1.f;
    float B0=0,D0=0,E0=0, B1=0,D1=0,E1=0, B2=0,D2=0,E2=0, B3=0,D3=0,E3=0;
#pragma unroll
    for (int r = 0; r < 16; ++r) {
        float t0x = (r < 14) ? mcx[r+2] : 0.f, t0y = (r < 14) ? mcy[r+2] : 0.f;
        float t1x = (r >= 2) ? mcx[r-2] : 0.f, t1y = (r >= 2) ? mcy[r-2] : 0.f;
        float t2x = dppf<0x101>(mcx[r]) * mz7, t2y = dppf<0x101>(mcy[r]) * mz7;
        float t3x = dppf<0x111>(mcx[r]) * mz0, t3y = dppf<0x111>(mcy[r]) * mz0;
#define ACC2(tx, ty, Bx, Dx, Ex) { \
        float mix_ = (tx) * imx[r], miy_ = (ty) * imy[r]; \
        Bx += mix_ + miy_; \
        Dx += (tx)*(tx)*mix_ + (ty)*(ty)*miy_; \
        float ax_ = (tx)*mix_, ay_ = (ty)*miy_; \
        Ex += ax_*ax_ + ay_*ay_; }
        ACC2(t0x, t0y, B0, D0, E0)
        ACC2(t1x, t1y, B1, D1, E1)
        ACC2(t2x, t2y, B2, D2, E2)
        ACC2(t3x, t3y, B3, D3, E3)
#undef ACC2
    }
    float A0 = S1 - (mcx[0] + mcy[0] + mcx[1] + mcy[1]);
    float C0 = S2 - (mcx[0]*mcx[0] + mcy[0]*mcy[0] + mcx[1]*mcx[1] + mcy[1]*mcy[1]);
    float A1 = S1 - (mcx[14] + mcy[14] + mcx[15] + mcy[15]);
    float C1 = S2 - (mcx[14]*mcx[14] + mcy[14]*mcy[14] + mcx[15]*mcx[15] + mcy[15]*mcy[15]);
    float A2 = dppf<0x101>(S1) * mz7, C2 = dppf<0x101>(S2) * mz7;
    float A3 = dppf<0x111>(S1) * mz0, C3 = dppf<0x111>(S2) * mz0;

    // ---- 26 half-row reductions, all DPP on the VALU pipe ----
    c_acc = bfly8(c_acc); r_acc = bfly8(r_acc);
    e_acc = bfly8(e_acc); a_acc = bfly8(a_acc);
    float smc = bfly8(S1); smi = bfly8(smi);
    A0 = bfly8(A0); A1 = bfly8(A1); A2 = bfly8(A2); A3 = bfly8(A3);
    B0 = bfly8(B0); B1 = bfly8(B1); B2 = bfly8(B2); B3 = bfly8(B3);
    C0 = bfly8(C0); C1 = bfly8(C1); C2 = bfly8(C2); C3 = bfly8(C3);
    D0 = bfly8(D0); D1 = bfly8(D1); D2 = bfly8(D2); D3 = bfly8(D3);
    E0 = bfly8(E0); E1 = bfly8(E1); E2 = bfly8(E2); E3 = bfly8(E3);

    const float scale = smi / smc;

    // ---- dense store path: two 4-batch staging rounds (wave-private,
    //      barrier-free), bank-swizzled layout, SEPARATED output streams. ----
    float* wbuf = smem + w * ROUND_F;
    const int batchBase = blockIdx.x * 32 + w * 8;
    float* oib = out + (size_t)B * 256;

    // readback address: lane wants logical dwords [lane*4 .. +3] of batch c;
    // logical 32a+4b lives at physical 32a + 4*(b^a).
    const int aa = lane >> 3, bb = lane & 7;
    const int rdw = 32 * aa + 4 * (bb ^ aa);

#pragma unroll
    for (int half = 0; half < 2; ++half) {
        if ((q >> 2) == half) {
            float* wb = wbuf + (q & 3) * BATCH_F;
#pragma unroll
            for (int r = 0; r < 16; ++r) {
                // logical d = r*16 + 2l -> row a=r>>1, slot s=(r&1)*4+(l>>1)
                const int ar = r >> 1;
                const int sr = (r & 1) * 4 + (l >> 1);
                const int dw = 32 * ar + 4 * (sr ^ ar) + ((2 * l) & 3);
                vf2 mv; mv.x = mcx[r]; mv.y = mcy[r];
                *reinterpret_cast<vf2*>(wb + dw) = mv;
            }
            if (l == 0) wbuf[4 * BATCH_F + (q & 3)] = scale;
        }
        asm volatile("s_waitcnt lgkmcnt(0)" ::: "memory");
        vf4 scv = *reinterpret_cast<const vf4*>(wbuf + 4 * BATCH_F);
        // stream 1: mc — 4KB dense per wave round
#pragma unroll
        for (int c = 0; c < 4; ++c) {
            const int bbch = batchBase + half * 4 + c;
            vf4 v = *reinterpret_cast<const vf4*>(wbuf + c * BATCH_F + rdw);
            __builtin_nontemporal_store(v,
                reinterpret_cast<vf4*>(out + (size_t)bbch * 256) + lane);
        }
        // stream 2: out_image = mc * scale — 4KB dense per wave round
#pragma unroll
        for (int c = 0; c < 4; ++c) {
            const int bbch = batchBase + half * 4 + c;
            vf4 v = *reinterpret_cast<const vf4*>(wbuf + c * BATCH_F + rdw);
            float sc = (c == 0) ? scv.x : (c == 1) ? scv.y : (c == 2) ? scv.z : scv.w;
            __builtin_nontemporal_store(v * sc,
                reinterpret_cast<vf4*>(oib + (size_t)bbch * 256) + lane);
        }
        asm volatile("" ::: "memory");
    }

    if (l == 0) {
        float m0 = B0 / A0, m1 = B1 / A1, m2 = B2 / A2, m3 = B3 / A3;
        float v0 = (E0 - 2.f * m0 * D0 + m0 * m0 * C0) / A0;
        float v1 = (E1 - 2.f * m1 * D1 + m1 * m1 * C1) / A1;
        float v2 = (E2 - 2.f * m2 * D2 + m2 * m2 * C2) / A2;
        float v3 = (E3 - 2.f * m3 * D3 + m3 * m3 * C3) / A3;
        float fm = 0.25f * (m0 + m1 + m2 + m3);
        float dm0 = m0 - fm, dm1 = m1 - fm, dm2 = m2 - fm, dm3 = m3 - fm;
        float vm = 0.25f * (dm0*dm0 + dm1*dm1 + dm2*dm2 + dm3*dm3);
        float fv = 0.25f * (v0 + v1 + v2 + v3);
        float dv0 = v0 - fv, dv1 = v1 - fv, dv2 = v2 - fv, dv3 = v3 - fv;
        float vv = 0.25f * (dv0*dv0 + dv1*dv1 + dv2*dv2 + dv3*dv3);

        float* s = out + (size_t)B * 512;
        __builtin_nontemporal_store(c_acc * (1.f / 128.f), s + b);
        __builtin_nontemporal_store(-r_acc * (1.f / 256.f), s + (size_t)B + b);
        __builtin_nontemporal_store(0.5f * (vm + vv), s + 2*(size_t)B + b);
        __builtin_nontemporal_store(e_acc * (1.f / 256.f), s + 3*(size_t)B + b);
        __builtin_nontemporal_store(a_acc * (1.f / 256.f), s + 4*(size_t)B + b);
    }
}

extern "C" void kernel_launch(void* const* d_in, const int* in_sizes, int n_in,
                              void* d_out, int out_size, void* d_ws, size_t ws_size,
                              hipStream_t stream) {
    const float* img = (const float*)d_in[0];
    const float* mn  = (const float*)d_in[1];
    const float* mo  = (const float*)d_in[2];
    float* out = (float*)d_out;
    const int B = in_sizes[0] / 256;
    const int blocks = (B + 31) / 32;   // 32 batches per 256-thread block
    apply_area_kernel<<<blocks, 256, 0, stream>>>(img, mn, mo, out, B);
}